// Round 1
// baseline (698.496 us; speedup 1.0000x reference)
//
#include <hip/hip_runtime.h>
#include <math.h>

#define NMOL   1024
#define NATOM  128
#define NDIM   129      // n + 1 (bordered KKT system)
#define NCOL   130      // NDIM + 1 RHS column
#define STRIDE 131      // odd stride: conflict-free column walks
#define NELEM  10
#define BLOCK  256

// LDS layout (floats): A[NDIM*STRIDE] | px,py,pz[NATOM] | sigma[NATOM] | diag[NATOM] | x[NDIM]
#define SMEM_FLOATS (NDIM*STRIDE + 3*NATOM + NATOM + NATOM + NDIM)
#define SMEM_BYTES  (SMEM_FLOATS * sizeof(float))

__global__ __launch_bounds__(BLOCK) void ceq_solve_kernel(
    const float* __restrict__ eneg,
    const float* __restrict__ positions,
    const float* __restrict__ node_attrs,
    const float* __restrict__ hardness,
    const float* __restrict__ total_charge,
    const int*   __restrict__ atomic_numbers,
    float* __restrict__ out)
{
    extern __shared__ float smem[];
    float* A  = smem;                       // NDIM x STRIDE
    float* px = A  + NDIM * STRIDE;
    float* py = px + NATOM;
    float* pz = py + NATOM;
    float* sg = pz + NATOM;                 // sigma = r^2
    float* dg = sg + NATOM;                 // diagonal values
    float* sx = dg + NATOM;                 // solution
    __shared__ int   s_piv;
    __shared__ float s_xk;

    const int m    = blockIdx.x;
    const int tid  = threadIdx.x;
    const int base = m * NATOM;

    // ---- per-atom precompute ----
    if (tid < NATOM) {
        const int i = tid;
        const int Z = atomic_numbers[base + i];
        const float r = 0.3f + 0.02f * (float)Z;   // synthetic covalent radii table
        sg[i] = r * r;
        const float* na = node_attrs + (size_t)(base + i) * NELEM;
        float best = na[0]; int bi = 0;
        #pragma unroll
        for (int e = 1; e < NELEM; ++e) {
            float v = na[e];
            if (v > best) { best = v; bi = e; }    // first-max, matches jnp.argmax
        }
        dg[i] = hardness[bi] + 0.5641895835477563f / r;   // h + 1/(sqrt(pi)*r)
        const float* p = positions + (size_t)(base + i) * 3;
        px[i] = p[0]; py[i] = p[1]; pz[i] = p[2];
    }
    __syncthreads();

    // ---- fill A (NDIM x NCOL: matrix + RHS column) ----
    for (int idx = tid; idx < NDIM * NCOL; idx += BLOCK) {
        const int i = idx / NCOL;
        const int j = idx - i * NCOL;
        float v;
        if (j == NDIM) {                      // RHS column
            v = (i < NATOM) ? -eneg[base + i] : total_charge[m];
        } else if (i == NATOM || j == NATOM) {
            v = 1.0f;                         // charge-conservation border
        } else if (i == j) {
            v = dg[i];
        } else {
            const float dx = px[i] - px[j];
            const float dy = py[i] - py[j];
            const float dz = pz[i] - pz[j];
            const float d  = sqrtf(dx*dx + dy*dy + dz*dz);
            const float g  = sqrtf(sg[i] + sg[j]);
            v = erff(d / (1.4142135623730951f * g)) / d;
        }
        A[i * STRIDE + j] = v;
    }
    __syncthreads();

    // ---- LU with partial pivoting, RHS carried in column NDIM ----
    for (int k = 0; k < NDIM; ++k) {
        // pivot search: wave 0, first-max tie-break (LAPACK isamax semantics)
        if (tid < 64) {
            float bv = -1.0f; int bidx = NDIM;
            const int i1 = k + tid;
            if (i1 < NDIM) { bv = fabsf(A[i1 * STRIDE + k]); bidx = i1; }
            const int i2 = i1 + 64;
            if (i2 < NDIM) {
                const float v2 = fabsf(A[i2 * STRIDE + k]);
                if (v2 > bv) { bv = v2; bidx = i2; }
            }
            #pragma unroll
            for (int off = 32; off; off >>= 1) {
                const float ov = __shfl_xor(bv, off);
                const int   oi = __shfl_xor(bidx, off);
                if (ov > bv || (ov == bv && oi < bidx)) { bv = ov; bidx = oi; }
            }
            if (tid == 0) s_piv = bidx;
        }
        __syncthreads();
        const int p = s_piv;
        if (p != k) {                          // swap rows k<->p over live columns
            for (int j = k + tid; j < NCOL; j += BLOCK) {
                const float t = A[k * STRIDE + j];
                A[k * STRIDE + j] = A[p * STRIDE + j];
                A[p * STRIDE + j] = t;
            }
        }
        __syncthreads();
        // rank-1 trailing update, one row per thread; pivot row reads broadcast
        const int i = k + 1 + tid;
        if (i < NDIM) {
            const float mult = A[i * STRIDE + k] / A[k * STRIDE + k];
            for (int j = k + 1; j < NCOL; ++j) {
                A[i * STRIDE + j] -= mult * A[k * STRIDE + j];
            }
        }
        __syncthreads();
    }

    // ---- back substitution ----
    for (int k = NDIM - 1; k >= 0; --k) {
        if (tid == 0) {
            const float xk = A[k * STRIDE + NDIM] / A[k * STRIDE + k];
            s_xk = xk; sx[k] = xk;
        }
        __syncthreads();
        if (tid < k) {
            A[tid * STRIDE + NDIM] -= A[tid * STRIDE + k] * s_xk;
        }
        __syncthreads();
    }

    if (tid < NATOM) out[base + tid] = sx[tid];
}

extern "C" void kernel_launch(void* const* d_in, const int* in_sizes, int n_in,
                              void* d_out, int out_size, void* d_ws, size_t ws_size,
                              hipStream_t stream) {
    const float* eneg           = (const float*)d_in[0];
    const float* positions      = (const float*)d_in[1];
    const float* node_attrs     = (const float*)d_in[2];
    const float* hardness       = (const float*)d_in[3];
    const float* total_charge   = (const float*)d_in[4];
    // d_in[5] = batch (unused: equal-sized sorted molecules)
    const int*   atomic_numbers = (const int*)d_in[6];
    float* out = (float*)d_out;

    // raise dynamic LDS limit above the 64 KB default (needs ~70.7 KB)
    (void)hipFuncSetAttribute((const void*)ceq_solve_kernel,
                              hipFuncAttributeMaxDynamicSharedMemorySize,
                              (int)SMEM_BYTES);

    ceq_solve_kernel<<<NMOL, BLOCK, SMEM_BYTES, stream>>>(
        eneg, positions, node_attrs, hardness, total_charge, atomic_numbers, out);
}

// Round 2
// 450.743 us; speedup vs baseline: 1.5497x; 1.5497x over previous
//
#include <hip/hip_runtime.h>
#include <math.h>

#define NMOL   1024
#define NATOM  128
#define NDIM   129      // n + 1 (bordered KKT system)
#define RHSCOL 129      // RHS lives in column 129
#define STRIDE 132      // multiple of 4 -> 16B-aligned float4 rows; cols 130,131 pad
#define NCHUNK 33       // STRIDE / 4
#define NELEM  10
#define BLOCK  256

typedef __attribute__((ext_vector_type(4))) float f4;

// LDS: A[NDIM*STRIDE] | px,py,pz,sg,dg[NATOM] | sx[NDIM]
#define SMEM_FLOATS (NDIM*STRIDE + 5*NATOM + NDIM)
#define SMEM_BYTES  (SMEM_FLOATS * sizeof(float))

__global__ __launch_bounds__(BLOCK) void ceq_solve_kernel(
    const float* __restrict__ eneg,
    const float* __restrict__ positions,
    const float* __restrict__ node_attrs,
    const float* __restrict__ hardness,
    const float* __restrict__ total_charge,
    const int*   __restrict__ atomic_numbers,
    float* __restrict__ out)
{
    extern __shared__ float smem[];
    float* A  = smem;                       // NDIM x STRIDE
    float* px = A  + NDIM * STRIDE;
    float* py = px + NATOM;
    float* pz = py + NATOM;
    float* sg = pz + NATOM;                 // sigma = r^2
    float* dg = sg + NATOM;                 // diagonal values
    float* sx = dg + NATOM;                 // solution

    const int m    = blockIdx.x;
    const int tid  = threadIdx.x;
    const int base = m * NATOM;

    // ---- per-atom precompute ----
    if (tid < NATOM) {
        const int i = tid;
        const int Z = atomic_numbers[base + i];
        const float r = 0.3f + 0.02f * (float)Z;
        sg[i] = r * r;
        const float* na = node_attrs + (size_t)(base + i) * NELEM;
        float best = na[0]; int bi = 0;
        #pragma unroll
        for (int e = 1; e < NELEM; ++e) {
            float v = na[e];
            if (v > best) { best = v; bi = e; }    // first-max, matches jnp.argmax
        }
        dg[i] = hardness[bi] + 0.5641895835477563f / r;   // h + 1/(sqrt(pi)*r)
        const float* p = positions + (size_t)(base + i) * 3;
        px[i] = p[0]; py[i] = p[1]; pz[i] = p[2];
    }
    __syncthreads();

    // ---- fill A (incl. RHS col 129; pad cols 130,131 zeroed) ----
    for (int idx = tid; idx < NDIM * STRIDE; idx += BLOCK) {
        const int i = idx / STRIDE;
        const int j = idx - i * STRIDE;
        float v;
        if (j >= 130) {
            v = 0.0f;                         // pad
        } else if (j == RHSCOL) {
            v = (i < NATOM) ? -eneg[base + i] : total_charge[m];
        } else if (i == NATOM || j == NATOM) {
            v = 1.0f;                         // charge-conservation border
        } else if (i == j) {
            v = dg[i];
        } else {
            const float dx = px[i] - px[j];
            const float dy = py[i] - py[j];
            const float dz = pz[i] - pz[j];
            const float d  = sqrtf(dx*dx + dy*dy + dz*dz);
            const float g  = sqrtf(sg[i] + sg[j]);
            v = erff(d / (1.4142135623730951f * g)) / d;
        }
        A[idx] = v;
    }
    __syncthreads();

    // ---- unpivoted LU (SPD leading block => stable), RHS carried along ----
    // 256 threads = 128 rows x 2 column-parity halves; float4 chunks.
    const int r    = tid & 127;
    const int half = tid >> 7;
    for (int k = 0; k < NDIM - 1; ++k) {
        const int rows = NDIM - 1 - k;        // 128-k
        if (r < rows) {
            const int i = k + 1 + r;
            float*       Ai = A + i * STRIDE;
            const float* Ak = A + k * STRIDE;
            const float mult = Ai[k] / Ak[k]; // Ak[k], Ai[k] broadcast/col reads
            const int c0 = (k + 1) >> 2;      // first live chunk (may be partial)
            for (int c = c0 + half; c < NCHUNK; c += 2) {
                f4 p = *(const f4*)(Ak + 4 * c);
                f4 a = *(const f4*)(Ai + 4 * c);
                f4 u = a - p * mult;
                if (c == c0) {                // mask j <= k: write back original
                    const int jb = 4 * c;     // (same-value write: benign)
                    if (jb + 0 <= k) u.x = a.x;
                    if (jb + 1 <= k) u.y = a.y;
                    if (jb + 2 <= k) u.z = a.z;
                    // jb+3 <= k impossible: 4*c0+3 >= k+1
                }
                *(f4*)(Ai + 4 * c) = u;
            }
        }
        __syncthreads();
    }

    // ---- back substitution: RHS in registers, 1 barrier per step ----
    float rhs = 0.0f;
    if (tid < NDIM) rhs = A[tid * STRIDE + RHSCOL];
    if (tid == NDIM - 1) sx[NDIM - 1] = rhs / A[(NDIM - 1) * STRIDE + (NDIM - 1)];
    __syncthreads();
    for (int k = NDIM - 1; k > 0; --k) {
        const float xk = sx[k];
        if (tid < k) {
            rhs -= A[tid * STRIDE + k] * xk;
            if (tid == k - 1) sx[k - 1] = rhs / A[tid * STRIDE + tid];
        }
        __syncthreads();
    }

    if (tid < NATOM) out[base + tid] = sx[tid];
}

extern "C" void kernel_launch(void* const* d_in, const int* in_sizes, int n_in,
                              void* d_out, int out_size, void* d_ws, size_t ws_size,
                              hipStream_t stream) {
    const float* eneg           = (const float*)d_in[0];
    const float* positions      = (const float*)d_in[1];
    const float* node_attrs     = (const float*)d_in[2];
    const float* hardness       = (const float*)d_in[3];
    const float* total_charge   = (const float*)d_in[4];
    // d_in[5] = batch (unused: equal-sized sorted molecules)
    const int*   atomic_numbers = (const int*)d_in[6];
    float* out = (float*)d_out;

    // dynamic LDS ~70.5 KB > 64 KB default
    (void)hipFuncSetAttribute((const void*)ceq_solve_kernel,
                              hipFuncAttributeMaxDynamicSharedMemorySize,
                              (int)SMEM_BYTES);

    ceq_solve_kernel<<<NMOL, BLOCK, SMEM_BYTES, stream>>>(
        eneg, positions, node_attrs, hardness, total_charge, atomic_numbers, out);
}

// Round 3
// 268.236 us; speedup vs baseline: 2.6040x; 1.6804x over previous
//
#include <hip/hip_runtime.h>
#include <math.h>

#define NMOL   1024
#define NATOM  128
#define NDIM   129      // n + 1 (bordered KKT system)
#define RHSCOL 129      // RHS lives in column 129
#define STRIDE 132      // multiple of 4 -> 16B-aligned float4 rows; cols 130,131 pad (zero)
#define NCHUNK 33       // STRIDE / 4
#define NELEM  10
#define BLOCK  256
#define PW     8        // panel width
#define NPANEL 16       // 16*8 = 128 eliminations; row 128 closed by back-sub

typedef __attribute__((ext_vector_type(4))) float f4;

// LDS: A[NDIM*STRIDE] | px,py,pz,sg,dg[NATOM] | sx[NDIM]
#define SMEM_FLOATS (NDIM*STRIDE + 5*NATOM + NDIM)
#define SMEM_BYTES  (SMEM_FLOATS * sizeof(float))

__global__ __launch_bounds__(BLOCK) void ceq_solve_kernel(
    const float* __restrict__ eneg,
    const float* __restrict__ positions,
    const float* __restrict__ node_attrs,
    const float* __restrict__ hardness,
    const float* __restrict__ total_charge,
    const int*   __restrict__ atomic_numbers,
    float* __restrict__ out)
{
    extern __shared__ float smem[];
    float* A  = smem;                       // NDIM x STRIDE
    float* px = A  + NDIM * STRIDE;
    float* py = px + NATOM;
    float* pz = py + NATOM;
    float* sg = pz + NATOM;                 // sigma = r^2
    float* dg = sg + NATOM;                 // diagonal values
    float* sx = dg + NATOM;                 // solution [NDIM]

    const int m    = blockIdx.x;
    const int tid  = threadIdx.x;
    const int lane = tid & 63;
    const int wid  = tid >> 6;
    const int base = m * NATOM;

    // ---- per-atom precompute ----
    if (tid < NATOM) {
        const int i = tid;
        const int Z = atomic_numbers[base + i];
        const float r = 0.3f + 0.02f * (float)Z;
        sg[i] = r * r;
        const float* na = node_attrs + (size_t)(base + i) * NELEM;
        float best = na[0]; int bi = 0;
        #pragma unroll
        for (int e = 1; e < NELEM; ++e) {
            float v = na[e];
            if (v > best) { best = v; bi = e; }    // first-max, matches jnp.argmax
        }
        dg[i] = hardness[bi] + 0.5641895835477563f / r;   // h + 1/(sqrt(pi)*r)
        const float* p = positions + (size_t)(base + i) * 3;
        px[i] = p[0]; py[i] = p[1]; pz[i] = p[2];
    }
    __syncthreads();

    // ---- fill A (incl. RHS col 129; pad cols 130,131 zeroed) ----
    for (int idx = tid; idx < NDIM * STRIDE; idx += BLOCK) {
        const int i = idx / STRIDE;
        const int j = idx - i * STRIDE;
        float v;
        if (j >= 130) {
            v = 0.0f;                         // pad (must stay zero: f4 GEMM touches it)
        } else if (j == RHSCOL) {
            v = (i < NATOM) ? -eneg[base + i] : total_charge[m];
        } else if (i == NATOM || j == NATOM) {
            v = 1.0f;                         // charge-conservation border
        } else if (i == j) {
            v = dg[i];
        } else {
            const float dx = px[i] - px[j];
            const float dy = py[i] - py[j];
            const float dz = pz[i] - pz[j];
            const float d  = sqrtf(dx*dx + dy*dy + dz*dz);
            const float g  = sqrtf(sg[i] + sg[j]);
            v = erff(d / (1.4142135623730951f * g)) / d;
        }
        A[idx] = v;
    }
    __syncthreads();

    // ================= blocked unpivoted LU (SPD leading block) =================
    for (int p = 0; p < NPANEL; ++p) {
        const int k0 = PW * p;

        // ---- (a) panel factor: wave 0, register-resident, shuffle broadcasts ----
        if (wid == 0) {
            float rg[3][PW];
            int   rowi[3];
            #pragma unroll
            for (int s = 0; s < 3; ++s) {
                const int i = k0 + lane + 64 * s;
                rowi[s] = i;
                if (i < NDIM) {
                    f4 lo = *(const f4*)(A + i * STRIDE + k0);
                    f4 hi = *(const f4*)(A + i * STRIDE + k0 + 4);
                    rg[s][0] = lo.x; rg[s][1] = lo.y; rg[s][2] = lo.z; rg[s][3] = lo.w;
                    rg[s][4] = hi.x; rg[s][5] = hi.y; rg[s][6] = hi.z; rg[s][7] = hi.w;
                } else {
                    #pragma unroll
                    for (int j = 0; j < PW; ++j) rg[s][j] = 0.0f;
                }
            }
            #pragma unroll
            for (int kk = 0; kk < PW; ++kk) {
                float pr[PW];
                #pragma unroll
                for (int j = kk; j < PW; ++j) pr[j] = __shfl(rg[0][j], kk); // pivot row (lane kk, s=0)
                const float dinv = 1.0f / pr[kk];
                #pragma unroll
                for (int s = 0; s < 3; ++s) {
                    if (rowi[s] > k0 + kk && rowi[s] < NDIM) {
                        const float mult = rg[s][kk] * dinv;
                        rg[s][kk] = mult;                       // store L
                        #pragma unroll
                        for (int j = kk + 1; j < PW; ++j) rg[s][j] -= mult * pr[j];
                    }
                }
            }
            #pragma unroll
            for (int s = 0; s < 3; ++s) {
                const int i = rowi[s];
                if (i < NDIM) {
                    f4 lo = { rg[s][0], rg[s][1], rg[s][2], rg[s][3] };
                    f4 hi = { rg[s][4], rg[s][5], rg[s][6], rg[s][7] };
                    *(f4*)(A + i * STRIDE + k0)     = lo;
                    *(f4*)(A + i * STRIDE + k0 + 4) = hi;
                }
            }
        }
        __syncthreads();

        // ---- (b) TRSM: U rows k0..k0+7, cols >= k0+8 (incl RHS). 1 thread/col ----
        const int ncols = RHSCOL - (k0 + PW) + 1;   // 122 - 8p
        if (tid < ncols) {
            const int j = k0 + PW + tid;
            float u[PW];
            #pragma unroll
            for (int kk = 0; kk < PW; ++kk) u[kk] = A[(k0 + kk) * STRIDE + j];
            #pragma unroll
            for (int kk = 1; kk < PW; ++kk) {
                float acc = u[kk];
                #pragma unroll
                for (int t = 0; t < kk; ++t)
                    acc -= A[(k0 + kk) * STRIDE + (k0 + t)] * u[t];  // L broadcast
                u[kk] = acc;
            }
            #pragma unroll
            for (int kk = 0; kk < PW; ++kk) A[(k0 + kk) * STRIDE + j] = u[kk];
        }
        __syncthreads();

        // ---- (c) GEMM trailing update: rows >= k0+8, chunks c in [2p+2, 32] ----
        {
            const int i0 = k0 + PW + lane;
            const int i1 = i0 + 64;
            const bool v0 = i0 < NDIM;
            const bool v1 = i1 < NDIM;
            const int c_lo = (k0 + PW) >> 2;        // 2p+2, exactly chunk-aligned
            float L0[PW], L1[PW];
            if (v0) {
                f4 lo = *(const f4*)(A + i0 * STRIDE + k0);
                f4 hi = *(const f4*)(A + i0 * STRIDE + k0 + 4);
                L0[0]=lo.x; L0[1]=lo.y; L0[2]=lo.z; L0[3]=lo.w;
                L0[4]=hi.x; L0[5]=hi.y; L0[6]=hi.z; L0[7]=hi.w;
            }
            if (v1) {
                f4 lo = *(const f4*)(A + i1 * STRIDE + k0);
                f4 hi = *(const f4*)(A + i1 * STRIDE + k0 + 4);
                L1[0]=lo.x; L1[1]=lo.y; L1[2]=lo.z; L1[3]=lo.w;
                L1[4]=hi.x; L1[5]=hi.y; L1[6]=hi.z; L1[7]=hi.w;
            }
            for (int c = c_lo + wid; c < NCHUNK; c += 4) {
                f4 U[PW];
                #pragma unroll
                for (int t = 0; t < PW; ++t)
                    U[t] = *(const f4*)(A + (k0 + t) * STRIDE + 4 * c); // wave-uniform -> broadcast
                if (v0) {
                    f4 acc = *(const f4*)(A + i0 * STRIDE + 4 * c);
                    #pragma unroll
                    for (int t = 0; t < PW; ++t) acc -= U[t] * L0[t];
                    *(f4*)(A + i0 * STRIDE + 4 * c) = acc;
                }
                if (v1) {
                    f4 acc = *(const f4*)(A + i1 * STRIDE + 4 * c);
                    #pragma unroll
                    for (int t = 0; t < PW; ++t) acc -= U[t] * L1[t];
                    *(f4*)(A + i1 * STRIDE + 4 * c) = acc;
                }
            }
        }
        __syncthreads();
    }

    // ================= blocked back substitution =================
    // x[128] (border unknown), then update all RHS rows once
    if (tid == 0) sx[128] = A[128 * STRIDE + RHSCOL] / A[128 * STRIDE + 128];
    __syncthreads();
    if (tid < 128) A[tid * STRIDE + RHSCOL] -= A[tid * STRIDE + 128] * sx[128];
    __syncthreads();

    for (int pb = NPANEL - 1; pb >= 0; --pb) {
        const int k0 = PW * pb;
        if (tid == 0) {                      // serial 8x8 upper-tri solve
            float xx[PW];
            #pragma unroll
            for (int kk = PW - 1; kk >= 0; --kk) {
                float acc = A[(k0 + kk) * STRIDE + RHSCOL];
                #pragma unroll
                for (int j = kk + 1; j < PW; ++j)
                    acc -= A[(k0 + kk) * STRIDE + (k0 + j)] * xx[j];
                xx[kk] = acc / A[(k0 + kk) * STRIDE + (k0 + kk)];
                sx[k0 + kk] = xx[kk];
            }
        }
        __syncthreads();
        if (tid < k0) {                      // rank-8 RHS update, f4 row reads
            f4 a0 = *(const f4*)(A + tid * STRIDE + k0);
            f4 a1 = *(const f4*)(A + tid * STRIDE + k0 + 4);
            float acc = A[tid * STRIDE + RHSCOL];
            acc -= a0.x * sx[k0]     + a0.y * sx[k0 + 1]
                 + a0.z * sx[k0 + 2] + a0.w * sx[k0 + 3]
                 + a1.x * sx[k0 + 4] + a1.y * sx[k0 + 5]
                 + a1.z * sx[k0 + 6] + a1.w * sx[k0 + 7];
            A[tid * STRIDE + RHSCOL] = acc;
        }
        __syncthreads();
    }

    if (tid < NATOM) out[base + tid] = sx[tid];
}

extern "C" void kernel_launch(void* const* d_in, const int* in_sizes, int n_in,
                              void* d_out, int out_size, void* d_ws, size_t ws_size,
                              hipStream_t stream) {
    const float* eneg           = (const float*)d_in[0];
    const float* positions      = (const float*)d_in[1];
    const float* node_attrs     = (const float*)d_in[2];
    const float* hardness       = (const float*)d_in[3];
    const float* total_charge   = (const float*)d_in[4];
    // d_in[5] = batch (unused: equal-sized sorted molecules)
    const int*   atomic_numbers = (const int*)d_in[6];
    float* out = (float*)d_out;

    // dynamic LDS ~70.5 KB > 64 KB default
    (void)hipFuncSetAttribute((const void*)ceq_solve_kernel,
                              hipFuncAttributeMaxDynamicSharedMemorySize,
                              (int)SMEM_BYTES);

    ceq_solve_kernel<<<NMOL, BLOCK, SMEM_BYTES, stream>>>(
        eneg, positions, node_attrs, hardness, total_charge, atomic_numbers, out);
}